// Round 8
// baseline (157.543 us; speedup 1.0000x reference)
//
#include <hip/hip_runtime.h>
#include <hip/hip_bf16.h>
#include <cstdint>
#include <cmath>

// Problem constants — inputs/outputs are fp32 (verified R1 vs R2).
// LESSON (R5): cooperative grid.sync() ~50 us on MI355X — use kernel bounds.
// LESSON (R6/R7): scan topology cheap; VALU fp32->bf16 staging == separate
// convert in cost; launch gap ~5 us/boundary. Attack round-trips + launches.
#define T_SEQ 16384
#define DMODEL 512
#define NCHUNK 512        // scan chunks (= T_SEQ/LCHUNK)
#define LCHUNK 32
#define W_N    (DMODEL * DMODEL)
#define N4_W   (W_N / 4)
#define N4_W2  (2 * N4_W)

typedef __bf16 bf16x8 __attribute__((ext_vector_type(8)));
typedef float  f32x4  __attribute__((ext_vector_type(4)));

using bf16 = __hip_bfloat16;

__device__ __forceinline__ void load_lds16(const void* g, void* l) {
    __builtin_amdgcn_global_load_lds((const __attribute__((address_space(1))) void*)g,
                                     (__attribute__((address_space(3))) void*)l,
                                     16, 0, 0);
}

__device__ __forceinline__ unsigned short f2bf(float f) {
    union { float f; unsigned u; } v; v.f = f;
    const unsigned r = (v.u + 0x7FFFu + ((v.u >> 16) & 1u)) >> 16;
    return (unsigned short)r;
}
__device__ __forceinline__ float bf2f(unsigned short u) {
    union { unsigned u; float f; } v; v.u = ((unsigned)u) << 16;
    return v.f;
}

// ordered pair-combine: first=(fA,fB) then second=(sA,sB)
__device__ __forceinline__ void comb(float& A, float& B, float fA, float fB,
                                     float sA, float sB) {
    A = fA * sA;
    B = sA * fB + sB;
}

// ---------------------------------------------------------------------------
// Kernel 0: convert Wz, Wh fp32 -> bf16 (Wo handled inside gemm_out_fused)
// ---------------------------------------------------------------------------
__global__ __launch_bounds__(256) void k_convert_w(
    const float* __restrict__ Wz, const float* __restrict__ Wh,
    bf16* __restrict__ Wz_c, bf16* __restrict__ Wh_c)
{
    const int i = blockIdx.x * 256 + threadIdx.x;
    if (i >= N4_W2) return;
    const int w = i >> 16;
    const int o = i & 65535;
    const float* src = (w == 0) ? Wz : Wh;
    bf16* dst = (w == 0) ? Wz_c : Wh_c;
    const float4 v = ((const float4*)src)[o];
    ushort4 r;
    r.x = f2bf(v.x); r.y = f2bf(v.y); r.z = f2bf(v.z); r.w = f2bf(v.w);
    ((ushort4*)dst)[o] = r;
}

// ---------------------------------------------------------------------------
// Kernel 1: fused dual GEMM + scan phase 1 (unchanged from R7).
// ---------------------------------------------------------------------------
__global__ __launch_bounds__(256, 2) void gemm_zh(
    const float* __restrict__ xs, const bf16* __restrict__ Wz, const float* __restrict__ bz,
    const bf16* __restrict__ Wh, const float* __restrict__ bh,
    unsigned int* __restrict__ ab_ws,
    float* __restrict__ AaggT, float* __restrict__ BaggT)
{
    __shared__ __bf16 As[128 * 64];
    __shared__ __bf16 Zs[128 * 64];
    __shared__ __bf16 Hs[128 * 64];

    const int tid  = threadIdx.x;
    const int bm   = blockIdx.x;   // 0..127 (M tile)
    const int bn   = blockIdx.y;   // 0..3   (N tile)
    const int lane = tid & 63;
    const int wave = tid >> 6;
    const int wm   = wave >> 1;
    const int wn   = wave & 1;

    f32x4 accz[4][4], acch[4][4];
    #pragma unroll
    for (int i = 0; i < 4; ++i)
        #pragma unroll
        for (int j = 0; j < 4; ++j) {
            accz[i][j] = (f32x4){0.f, 0.f, 0.f, 0.f};
            acch[i][j] = (f32x4){0.f, 0.f, 0.f, 0.f};
        }

    const int row0 = tid >> 3;
    const int k8   = tid & 7;
    const bf16* zg = Wz + (size_t)(bn * 128) * DMODEL + k8 * 8;
    const bf16* hg = Wh + (size_t)(bn * 128) * DMODEL + k8 * 8;

    const int frow = tid >> 4;
    const int f4   = tid & 15;
    const float* xg = xs + ((size_t)(bm * 128) + frow) * DMODEL + f4 * 4;

    const int quad = lane >> 4;
    const int col  = lane & 15;

    for (int k0 = 0; k0 < DMODEL; k0 += 64) {
        #pragma unroll
        for (int it = 0; it < 4; ++it) {
            const int row   = row0 + it * 32;
            const int chunk = it * 256 + tid;
            load_lds16(zg + (size_t)row * DMODEL + k0, &Zs[chunk * 8]);
            load_lds16(hg + (size_t)row * DMODEL + k0, &Hs[chunk * 8]);
        }
        #pragma unroll
        for (int it2 = 0; it2 < 8; ++it2) {
            const int row = frow + it2 * 16;
            const float4 v = *(const float4*)(xg + (size_t)(it2 * 16) * DMODEL + k0);
            __hip_bfloat162 p0 = __float22bfloat162_rn(make_float2(v.x, v.y));
            __hip_bfloat162 p1 = __float22bfloat162_rn(make_float2(v.z, v.w));
            uint2 pk;
            pk.x = *(const unsigned*)&p0;
            pk.y = *(const unsigned*)&p1;
            *(uint2*)&As[row * 64 + f4 * 4] = pk;
        }
        __syncthreads();

        #pragma unroll
        for (int kk = 0; kk < 2; ++kk) {
            const int kb = kk * 32 + quad * 8;
            bf16x8 af[4], zf[4], hf[4];
            #pragma unroll
            for (int i = 0; i < 4; ++i) {
                const int am  = wm * 64 + i * 16 + col;
                const int bnr = wn * 64 + i * 16 + col;
                af[i] = *(const bf16x8*)&As[am * 64 + kb];
                zf[i] = *(const bf16x8*)&Zs[bnr * 64 + kb];
                hf[i] = *(const bf16x8*)&Hs[bnr * 64 + kb];
            }
            #pragma unroll
            for (int i = 0; i < 4; ++i)
                #pragma unroll
                for (int j = 0; j < 4; ++j) {
                    accz[i][j] = __builtin_amdgcn_mfma_f32_16x16x32_bf16(af[i], zf[j], accz[i][j], 0, 0, 0);
                    acch[i][j] = __builtin_amdgcn_mfma_f32_16x16x32_bf16(af[i], hf[j], acch[i][j], 0, 0, 0);
                }
        }
        __syncthreads();
    }

    const int c_lo = bm * 4 + wm * 2;
    #pragma unroll
    for (int j = 0; j < 4; ++j) {
        const int n = bn * 128 + wn * 64 + j * 16 + col;
        const float bzv = bz[n];
        const float bhv = bh[n];
        float cA[4], cB[4];
        #pragma unroll
        for (int i = 0; i < 4; ++i) {
            const int mbase = bm * 128 + wm * 64 + i * 16 + quad * 4;
            float A = 1.f, B = 0.f;
            #pragma unroll
            for (int r = 0; r < 4; ++r) {
                const float zpre = accz[i][j][r] + bzv;
                const float hpre = acch[i][j][r] + bhv;
                const float z = 1.f / (1.f + __expf(-zpre));
                const float a = 1.f - z;
                const float b = z * hpre;
                const size_t idx = (size_t)(mbase + r) * DMODEL + n;
                ab_ws[idx] = (unsigned)f2bf(a) | ((unsigned)f2bf(b) << 16);
                A = a * A;
                B = a * B + b;
            }
            cA[i] = A; cB[i] = B;
        }
        #pragma unroll
        for (int i = 0; i < 4; ++i) {
            float pA = __shfl_xor(cA[i], 16);
            float pB = __shfl_xor(cB[i], 16);
            const bool hi1 = quad & 1;
            comb(cA[i], cB[i], hi1 ? pA : cA[i], hi1 ? pB : cB[i],
                               hi1 ? cA[i] : pA, hi1 ? cB[i] : pB);
            pA = __shfl_xor(cA[i], 32);
            pB = __shfl_xor(cB[i], 32);
            const bool hi2 = quad >> 1;
            comb(cA[i], cB[i], hi2 ? pA : cA[i], hi2 ? pB : cB[i],
                               hi2 ? cA[i] : pA, hi2 ? cB[i] : pB);
        }
        float Alo, Blo, Ahi, Bhi;
        comb(Alo, Blo, cA[0], cB[0], cA[1], cB[1]);
        comb(Ahi, Bhi, cA[2], cB[2], cA[3], cB[3]);
        if (quad == 0) {
            AaggT[(size_t)n * NCHUNK + c_lo]     = Alo;
            BaggT[(size_t)n * NCHUNK + c_lo]     = Blo;
            AaggT[(size_t)n * NCHUNK + c_lo + 1] = Ahi;
            BaggT[(size_t)n * NCHUNK + c_lo + 1] = Bhi;
        }
    }
}

// ---------------------------------------------------------------------------
// Kernel 2: per-channel Hillis-Steele over NCHUNK chunk aggregates (unchanged)
// ---------------------------------------------------------------------------
__global__ __launch_bounds__(512) void scan_p2(
    const float* __restrict__ AaggT, const float* __restrict__ BaggT,
    float* __restrict__ HpreT)
{
    const int h = blockIdx.x;
    const int c = threadIdx.x;
    __shared__ float sA[NCHUNK], sB[NCHUNK];

    float A = AaggT[(size_t)h * NCHUNK + c];
    float B = BaggT[(size_t)h * NCHUNK + c];
    sA[c] = A; sB[c] = B;
    __syncthreads();

    for (int off = 1; off < NCHUNK; off <<= 1) {
        float pA = 1.f, pB = 0.f;
        if (c >= off) { pA = sA[c - off]; pB = sB[c - off]; }
        __syncthreads();
        const float nB = A * pB + B;   // uses old A
        const float nA = A * pA;
        A = nA; B = nB;
        sA[c] = A; sB[c] = B;
        __syncthreads();
    }
    const float hp = (c == 0) ? 0.f : sB[c - 1];
    HpreT[(size_t)h * NCHUNK + c] = hp;
}

// ---------------------------------------------------------------------------
// Kernel 3: fused scan_p3 + out-GEMM.  out = states @ Wo^T + bo (fp32).
// A-tile (states 128 t x 64 ch) is REPLAYED into LDS per k0 from ab_ws+HpreT:
// 256 threads = (4 chunks x 64 channels), 32 serial steps each, coalesced ab
// reads (L3-served for bn>0), 2-way-aliased bf16 ds_writes (free per m136).
// Wo staged fp32->bf16 via VALU (no separate convert).
// ---------------------------------------------------------------------------
__global__ __launch_bounds__(256, 2) void gemm_out_fused(
    const unsigned int* __restrict__ ab_ws, const float* __restrict__ HpreT,
    const float* __restrict__ Wo, const float* __restrict__ bo,
    float* __restrict__ out)
{
    __shared__ __bf16 As[128 * 64];
    __shared__ __bf16 Bs[128 * 64];

    const int tid  = threadIdx.x;
    const int bm   = blockIdx.x;   // 0..127
    const int bn   = blockIdx.y;   // 0..3
    const int lane = tid & 63;
    const int wave = tid >> 6;
    const int wm   = wave >> 1;
    const int wn   = wave & 1;

    f32x4 acc[4][4];
    #pragma unroll
    for (int i = 0; i < 4; ++i)
        #pragma unroll
        for (int j = 0; j < 4; ++j)
            acc[i][j] = (f32x4){0.f, 0.f, 0.f, 0.f};

    // Wo staging (fp32 -> bf16 VALU path)
    const int frow = tid >> 4;
    const int f4   = tid & 15;
    const float* wg = Wo + ((size_t)(bn * 128) + frow) * DMODEL + f4 * 4;

    // replay mapping: 4 chunks x 64 channels
    const int cl = tid >> 6;           // chunk-local 0..3
    const int hl = tid & 63;           // channel-local 0..63
    const int chunk = bm * 4 + cl;     // global chunk
    const int tbase = chunk * LCHUNK;  // global t start

    const int quad = lane >> 4;
    const int col  = lane & 15;

    for (int k0 = 0; k0 < DMODEL; k0 += 64) {
        // stage Wo tile
        #pragma unroll
        for (int it2 = 0; it2 < 8; ++it2) {
            const int row = frow + it2 * 16;
            const float4 v = *(const float4*)(wg + (size_t)(it2 * 16) * DMODEL + k0);
            __hip_bfloat162 p0 = __float22bfloat162_rn(make_float2(v.x, v.y));
            __hip_bfloat162 p1 = __float22bfloat162_rn(make_float2(v.z, v.w));
            uint2 pk;
            pk.x = *(const unsigned*)&p0;
            pk.y = *(const unsigned*)&p1;
            *(uint2*)&Bs[row * 64 + f4 * 4] = pk;
        }
        // replay states for channels k0+hl, timesteps tbase..tbase+32
        {
            const int h = k0 + hl;
            float H = HpreT[(size_t)h * NCHUNK + chunk];
            const unsigned int* ap = ab_ws + (size_t)tbase * DMODEL + h;
            #pragma unroll 8
            for (int i = 0; i < LCHUNK; ++i) {
                const unsigned u = ap[(size_t)i * DMODEL];
                const float a = bf2f((unsigned short)(u & 0xFFFFu));
                const float b = bf2f((unsigned short)(u >> 16));
                H = a * H + b;
                *(unsigned short*)&As[(cl * LCHUNK + i) * 64 + hl] = f2bf(H);
            }
        }
        __syncthreads();

        #pragma unroll
        for (int kk = 0; kk < 2; ++kk) {
            const int kb = kk * 32 + quad * 8;
            bf16x8 af[4], bf[4];
            #pragma unroll
            for (int i = 0; i < 4; ++i) {
                af[i] = *(const bf16x8*)&As[(wm * 64 + i * 16 + col) * 64 + kb];
                bf[i] = *(const bf16x8*)&Bs[(wn * 64 + i * 16 + col) * 64 + kb];
            }
            #pragma unroll
            for (int i = 0; i < 4; ++i)
                #pragma unroll
                for (int j = 0; j < 4; ++j)
                    acc[i][j] = __builtin_amdgcn_mfma_f32_16x16x32_bf16(af[i], bf[j], acc[i][j], 0, 0, 0);
        }
        __syncthreads();
    }

    #pragma unroll
    for (int j = 0; j < 4; ++j) {
        const int n = bn * 128 + wn * 64 + j * 16 + col;
        const float bov = bo[n];
        #pragma unroll
        for (int i = 0; i < 4; ++i) {
            const int mbase = bm * 128 + wm * 64 + i * 16 + quad * 4;
            #pragma unroll
            for (int r = 0; r < 4; ++r)
                out[(size_t)(mbase + r) * DMODEL + n] = acc[i][j][r] + bov;
        }
    }
}

// ---------------------------------------------------------------------------
extern "C" void kernel_launch(void* const* d_in, const int* in_sizes, int n_in,
                              void* d_out, int out_size, void* d_ws, size_t ws_size,
                              hipStream_t stream)
{
    const float* xs = (const float*)d_in[0];
    const float* Wz = (const float*)d_in[1];
    const float* bz = (const float*)d_in[2];
    const float* Wh = (const float*)d_in[3];
    const float* bh = (const float*)d_in[4];
    const float* Wo = (const float*)d_in[5];
    const float* bo = (const float*)d_in[6];
    float* out = (float*)d_out;

    char* w = (char*)d_ws;
    bf16*  Wz_c   = (bf16*) (w);                     //    524,288
    bf16*  Wh_c   = (bf16*) (w + 524288ull);         //    524,288
    unsigned int* ab_ws = (unsigned int*)(w + 1048576ull);   // 33,554,432
    float* AaggT  = (float*)(w + 34603008ull);       //  1,048,576
    float* BaggT  = (float*)(w + 35651584ull);       //  1,048,576
    float* HpreT  = (float*)(w + 36700160ull);       //  1,048,576

    k_convert_w<<<(N4_W2 + 255) / 256, 256, 0, stream>>>(Wz, Wh, Wz_c, Wh_c);
    gemm_zh<<<dim3(128, 4), 256, 0, stream>>>(xs, Wz_c, bz, Wh_c, bh, ab_ws, AaggT, BaggT);
    scan_p2<<<DMODEL, NCHUNK, 0, stream>>>(AaggT, BaggT, HpreT);
    gemm_out_fused<<<dim3(128, 4), 256, 0, stream>>>(ab_ws, HpreT, Wo, bo, out);
}